// Round 7
// baseline (6821.832 us; speedup 1.0000x reference)
//
#include <hip/hip_runtime.h>
#include <math.h>

#define BATCH 128
#define TSTEPS 4096
#define INDIM 13

// LDS layout (256 floats, fully zero-initialized each launch):
//  zL[0:96]  = smem+0    [x(13) | o0(35) | o1(23) | o2(6) | pad(19)] LSTM input
//  z0[0:64]  = smem+96   [x(13) | h0_lstm(35) | pad(16)]             CfC0 input
//  z1[0:64]  = smem+160  [o0(35) | h1_lstm(23) | pad(6)]             CfC1 input
//  z2[0:32]  = smem+224  [o1(23) | h2_lstm(6) | pad(3)]              CfC2 input

__device__ __forceinline__ float fsig(float x) {
    return __builtin_amdgcn_rcpf(1.f + __expf(-x));
}
__device__ __forceinline__ float ftanh(float x) {
    float s = fsig(x + x);
    return s + s - 1.f;
}
__device__ __forceinline__ float fsoftplus(float x) {
    return (x > 15.f) ? x : __logf(1.f + __expf(x));
}

// Park a value in an AGPR. Inline-asm results are NOT rematerializable and
// the "=a" class keeps them out of the VGPR allocator entirely — this is the
// remat-proof register residency rounds 3-6 failed to get from source tricks.
__device__ __forceinline__ float apark(float v) {
    float r;
    asm volatile("v_accvgpr_write_b32 %0, %1" : "=a"(r) : "v"(v));
    return r;
}
// Read an AGPR-parked value (2-cyc VALU, no memory latency).
__device__ __forceinline__ float aread(float a) {
    float r;
    asm volatile("v_accvgpr_read_b32 %0, %1" : "=v"(r) : "a"(a));
    return r;
}

// lane exchanges via DPP (VALU latency; no LDS pipe anywhere in the reduce)
__device__ __forceinline__ float qxor1(float v) {   // quad_perm [1,0,3,2]
    return __int_as_float(__builtin_amdgcn_update_dpp(
        0, __float_as_int(v), 0xB1, 0xF, 0xF, true));
}
__device__ __forceinline__ float qxor2(float v) {   // quad_perm [2,3,0,1]
    return __int_as_float(__builtin_amdgcn_update_dpp(
        0, __float_as_int(v), 0x4E, 0xF, 0xF, true));
}
__device__ __forceinline__ float hmir(float v) {    // row_half_mirror (8-lane)
    return __int_as_float(__builtin_amdgcn_update_dpp(
        0, __float_as_int(v), 0x141, 0xF, 0xF, true));
}
// 8-lane butterfly allreduce, all-DPP. After qxor1+qxor2 the quad is
// bit-uniform; hmir adds the other quad's (uniform) sum -> all 8 lanes
// bit-identical (commutative float adds are bitwise symmetric).
#define BFLY8(a) { a += qxor1(a); a += qxor2(a); a += hmir(a); }

// acc += dot(float4 zv, 4 AGPR-parked weights)
#define FMA4(acc, W, q, zv) { \
    acc += aread(W##_##q##_0) * zv.x; acc += aread(W##_##q##_1) * zv.y; \
    acc += aread(W##_##q##_2) * zv.z; acc += aread(W##_##q##_3) * zv.w; }

__global__ __launch_bounds__(512, 2)
void rnn_kernel(const float* __restrict__ x,
                const float* __restrict__ lstm_wi, const float* __restrict__ lstm_wh,
                const float* __restrict__ lstm_b,
                const float* __restrict__ c0w1, const float* __restrict__ c0w2,
                const float* __restrict__ c0wa, const float* __restrict__ c0wb,
                const float* __restrict__ c0b1, const float* __restrict__ c0b2,
                const float* __restrict__ c0ba, const float* __restrict__ c0bb,
                const float* __restrict__ c1w1, const float* __restrict__ c1w2,
                const float* __restrict__ c1wa, const float* __restrict__ c1wb,
                const float* __restrict__ c1b1, const float* __restrict__ c1b2,
                const float* __restrict__ c1ba, const float* __restrict__ c1bb,
                const float* __restrict__ c2w1, const float* __restrict__ c2w2,
                const float* __restrict__ c2wa, const float* __restrict__ c2wb,
                const float* __restrict__ c2b1, const float* __restrict__ c2b2,
                const float* __restrict__ c2ba, const float* __restrict__ c2bb,
                float* __restrict__ out)
{
    const int bb = blockIdx.x;
    const int t  = threadIdx.x;     // 0..511
    const int k  = t & 7;           // K-chunk slot within the octet
    const int u  = t >> 3;          // unit / row-group index 0..63

    __shared__ __align__(16) float smem[256];
    float* zL = smem;
    float* z0 = smem + 96;
    float* z1 = smem + 160;
    float* z2 = smem + 224;

    const long xbase = (long)bb * TSTEPS * INDIM;
    const long obase = (long)bb * TSTEPS * 6;

    // ---- LSTM weights: lane (u,k) holds cols [12k,12k+12) of all 4 gate rows
    auto lwf = [&](int A, int c) -> float {
        int r = A * 64 + u;
        return (c < 13) ? lstm_wi[r * 13 + c]
             : (c < 77) ? lstm_wh[r * 64 + (c - 13)] : 0.f;
    };
#define DEF_WL(A,q) \
    float wl##A##_##q##_0 = apark(lwf(A, 12*k + 4*q + 0)); \
    float wl##A##_##q##_1 = apark(lwf(A, 12*k + 4*q + 1)); \
    float wl##A##_##q##_2 = apark(lwf(A, 12*k + 4*q + 2)); \
    float wl##A##_##q##_3 = apark(lwf(A, 12*k + 4*q + 3));
    DEF_WL(0,0) DEF_WL(0,1) DEF_WL(0,2)
    DEF_WL(1,0) DEF_WL(1,1) DEF_WL(1,2)
    DEF_WL(2,0) DEF_WL(2,1) DEF_WL(2,2)
    DEF_WL(3,0) DEF_WL(3,1) DEF_WL(3,2)
#undef DEF_WL
    const float bL0 = apark(lstm_b[u]);
    const float bL1 = apark(lstm_b[64 + u]);
    const float bL2 = apark(lstm_b[128 + u]);
    const float bL3 = apark(lstm_b[192 + u]);

    // ---- CfC weights: octet groups (disjoint lane sets, one name overlay)
    // grp0 (u<35):  row u,    len 48, chunk 8 at 8k
    // grp1 (u<58):  row u-35, len 58, chunk 8 at 8k
    // grp2 (u>=58): row u-58, len 29, chunk 4 at 4k
    const int grp  = (u < 35) ? 0 : (u < 58) ? 1 : 2;
    const int row  = (grp == 0) ? u : (grp == 1) ? (u - 35) : (u - 58);
    const int rl   = (grp == 0) ? 48 : (grp == 1) ? 58 : 29;
    const int clen = (grp == 2) ? 4 : 8;
    const int cb   = (grp == 2) ? 4 * k : 8 * k;
    const float *W0p, *W1p, *W2p, *W3p;
    float bC0r, bC1r, bC2r, bC3r;
    if (grp == 0) {
        W0p = c0w1 + row * 48; W1p = c0w2 + row * 48;
        W2p = c0wa + row * 48; W3p = c0wb + row * 48;
        bC0r = c0b1[row]; bC1r = c0b2[row]; bC2r = c0ba[row]; bC3r = c0bb[row];
    } else if (grp == 1) {
        W0p = c1w1 + row * 58; W1p = c1w2 + row * 58;
        W2p = c1wa + row * 58; W3p = c1wb + row * 58;
        bC0r = c1b1[row]; bC1r = c1b2[row]; bC2r = c1ba[row]; bC3r = c1bb[row];
    } else {
        W0p = c2w1 + row * 29; W1p = c2w2 + row * 29;
        W2p = c2wa + row * 29; W3p = c2wb + row * 29;
        bC0r = c2b1[row]; bC1r = c2b2[row]; bC2r = c2ba[row]; bC3r = c2bb[row];
    }
    const float bC0 = apark(bC0r), bC1 = apark(bC1r);
    const float bC2 = apark(bC2r), bC3 = apark(bC3r);
    auto cwf = [&](const float* W, int c) -> float {
        int cc = cb + c;
        return (c < clen && cc < rl) ? W[cc] : 0.f;
    };
#define DEF_WC(A,q) \
    float wc##A##_##q##_0 = apark(cwf(W##A##p, 4*q + 0)); \
    float wc##A##_##q##_1 = apark(cwf(W##A##p, 4*q + 1)); \
    float wc##A##_##q##_2 = apark(cwf(W##A##p, 4*q + 2)); \
    float wc##A##_##q##_3 = apark(cwf(W##A##p, 4*q + 3));
    DEF_WC(0,0) DEF_WC(0,1)
    DEF_WC(1,0) DEF_WC(1,1)
    DEF_WC(2,0) DEF_WC(2,1)
    DEF_WC(3,0) DEF_WC(3,1)
#undef DEF_WC

    const bool pfl = (t >= 128 && t < 141);  // x-prefetch lanes (grp0, idle ph4)
    float creg = 0.f;                         // cell state, replicated per octet
    const float* xs = x + xbase + 13;         // scalar-advanced prefetch base

    // ---- init LDS: zero everything, then x_0 ----
    if (t < 256) smem[t] = 0.f;
    __syncthreads();
    if (t < 13) zL[t] = x[xbase + t];
    __syncthreads();

    #pragma unroll 1
    for (int ts = 0; ts < TSTEPS; ++ts) {
        // ---- phase 1: LSTM (all 512 lanes; K-split by k) ----
        float xn = 0.f;
        if (pfl && (ts + 1) < TSTEPS) xn = xs[t - 128];
        if (t >= 256 && t < 269) z0[t - 256] = zL[t - 256];  // x_t -> CfC0 input
        {
            const float4* zc = (const float4*)(zL + 12 * k);
            float4 q0 = zc[0], q1 = zc[1], q2 = zc[2];
            float a0 = 0.f, a1 = 0.f, a2 = 0.f, a3 = 0.f;
            FMA4(a0, wl0, 0, q0) FMA4(a0, wl0, 1, q1) FMA4(a0, wl0, 2, q2)
            FMA4(a1, wl1, 0, q0) FMA4(a1, wl1, 1, q1) FMA4(a1, wl1, 2, q2)
            FMA4(a2, wl2, 0, q0) FMA4(a2, wl2, 1, q1) FMA4(a2, wl2, 2, q2)
            FMA4(a3, wl3, 0, q0) FMA4(a3, wl3, 1, q1) FMA4(a3, wl3, 2, q2)
            BFLY8(a0) BFLY8(a1) BFLY8(a2) BFLY8(a3)
            a0 += aread(bL0); a1 += aread(bL1);
            a2 += aread(bL2); a3 += aread(bL3);           // ia, ig, fg, og
            float cn = creg * fsig(a2 + 1.f) + ftanh(a0) * fsig(a1);
            creg = cn;                      // bit-identical on all 8 octet lanes
            float hl = ftanh(cn) * fsig(a3);
            if (k == 0) {
                if (u < 35)      z0[13 + u] = hl;   // h0
                else if (u < 58) z1[u]      = hl;   // h1 at z1[35..57]
                else             z2[u - 35] = hl;   // h2 at z2[23..28]
            }
        }
        __syncthreads();

        // ---- phase 2: CfC layer 0 (grp0; chunk 8 over z0) ----
        if (grp == 0) {
            const float4* zc = (const float4*)(z0 + 8 * k);
            float4 p0 = zc[0], p1 = zc[1];
            float a0 = 0.f, a1 = 0.f, a2 = 0.f, a3 = 0.f;
            FMA4(a0, wc0, 0, p0) FMA4(a0, wc0, 1, p1)
            FMA4(a1, wc1, 0, p0) FMA4(a1, wc1, 1, p1)
            FMA4(a2, wc2, 0, p0) FMA4(a2, wc2, 1, p1)
            FMA4(a3, wc3, 0, p0) FMA4(a3, wc3, 1, p1)
            BFLY8(a0) BFLY8(a1) BFLY8(a2) BFLY8(a3)
            a0 += aread(bC0); a1 += aread(bC1);
            a2 += aread(bC2); a3 += aread(bC3);
            float tg = fsig(a2 + a3);
            float f1 = ftanh(a0), f2 = ftanh(a1);
            float o = f1 + tg * (f2 - f1);
            if (k == 0) { z1[row] = o; zL[13 + row] = o; }
        }
        __syncthreads();

        // ---- phase 3: CfC layer 1 (grp1; chunk 8 over z1) ----
        if (grp == 1) {
            const float4* zc = (const float4*)(z1 + 8 * k);
            float4 p0 = zc[0], p1 = zc[1];
            float a0 = 0.f, a1 = 0.f, a2 = 0.f, a3 = 0.f;
            FMA4(a0, wc0, 0, p0) FMA4(a0, wc0, 1, p1)
            FMA4(a1, wc1, 0, p0) FMA4(a1, wc1, 1, p1)
            FMA4(a2, wc2, 0, p0) FMA4(a2, wc2, 1, p1)
            FMA4(a3, wc3, 0, p0) FMA4(a3, wc3, 1, p1)
            BFLY8(a0) BFLY8(a1) BFLY8(a2) BFLY8(a3)
            a0 += aread(bC0); a1 += aread(bC1);
            a2 += aread(bC2); a3 += aread(bC3);
            float tg = fsig(a2 + a3);
            float f1 = ftanh(a0), f2 = ftanh(a1);
            float o = f1 + tg * (f2 - f1);
            if (k == 0) { z2[row] = o; zL[48 + row] = o; }
        }
        __syncthreads();

        // ---- phase 4: CfC layer 2 (grp2; chunk 4 over z2) + x commit ----
        if (grp == 2) {
            const float4* zc = (const float4*)(z2 + 4 * k);
            float4 p0 = zc[0];
            float a0 = 0.f, a1 = 0.f, a2 = 0.f, a3 = 0.f;
            FMA4(a0, wc0, 0, p0)
            FMA4(a1, wc1, 0, p0)
            FMA4(a2, wc2, 0, p0)
            FMA4(a3, wc3, 0, p0)
            BFLY8(a0) BFLY8(a1) BFLY8(a2) BFLY8(a3)
            a0 += aread(bC0); a1 += aread(bC1);
            a2 += aread(bC2); a3 += aread(bC3);
            float tg = fsig(a2 + a3);
            float f1 = ftanh(a0), f2 = ftanh(a1);
            float o = f1 + tg * (f2 - f1);
            if (k == 0) {
                out[obase + (long)ts * 6 + row] = o;  // raw cfc_out
                zL[71 + row] = o;                     // new h[58:64]
            }
        } else if (pfl) {
            zL[t - 128] = xn;                         // commit x_{t+1}
        }
        __syncthreads();
        xs += 13;
    }
}

// ---- head: rewrite pred in place, write unc ----
#define S_GW1 0
#define S_GB1 192
#define S_GW2 224
#define S_GB2 320
#define S_AW1 323
#define S_AB1 515
#define S_AW2 547
#define S_AB2 643
#define S_UW1 646
#define S_UB1 742
#define S_UW2 758
#define S_UB2 854
#define S_TOT 860

__global__ __launch_bounds__(256)
void head_kernel(const float* __restrict__ gw1, const float* __restrict__ gb1,
                 const float* __restrict__ gw2, const float* __restrict__ gb2,
                 const float* __restrict__ aw1, const float* __restrict__ ab1,
                 const float* __restrict__ aw2, const float* __restrict__ ab2,
                 const float* __restrict__ uw1, const float* __restrict__ ub1,
                 const float* __restrict__ uw2, const float* __restrict__ ub2,
                 float* __restrict__ out)
{
    __shared__ float s[S_TOT];
    const int t = threadIdx.x;
    if (t < 192) { s[S_GW1 + t] = gw1[t]; s[S_AW1 + t] = aw1[t]; }
    if (t < 96)  { s[S_GW2 + t] = gw2[t]; s[S_AW2 + t] = aw2[t];
                   s[S_UW1 + t] = uw1[t]; s[S_UW2 + t] = uw2[t]; }
    if (t < 32)  { s[S_GB1 + t] = gb1[t]; s[S_AB1 + t] = ab1[t]; }
    if (t < 16)  { s[S_UB1 + t] = ub1[t]; }
    if (t < 3)   { s[S_GB2 + t] = gb2[t]; s[S_AB2 + t] = ab2[t]; }
    if (t < 6)   { s[S_UB2 + t] = ub2[t]; }
    __syncthreads();

    const long p = (long)blockIdx.x * 256 + t;   // < B*T exactly
    const long base = p * 6;
    float m0 = out[base+0], m1 = out[base+1], m2 = out[base+2];
    float m3 = out[base+3], m4 = out[base+4], m5 = out[base+5];

    float gy0 = s[S_GB2+0], gy1 = s[S_GB2+1], gy2 = s[S_GB2+2];
    float ac0 = s[S_AB2+0], ac1 = s[S_AB2+1], ac2 = s[S_AB2+2];
    #pragma unroll
    for (int i = 0; i < 32; ++i) {
        float hg = s[S_GB1+i] + s[S_GW1+i*6+0]*m0 + s[S_GW1+i*6+1]*m1
                 + s[S_GW1+i*6+2]*m2 + s[S_GW1+i*6+3]*m3
                 + s[S_GW1+i*6+4]*m4 + s[S_GW1+i*6+5]*m5;
        hg = ftanh(hg);
        gy0 += s[S_GW2+i]*hg; gy1 += s[S_GW2+32+i]*hg; gy2 += s[S_GW2+64+i]*hg;
        float ha = s[S_AB1+i] + s[S_AW1+i*6+0]*m0 + s[S_AW1+i*6+1]*m1
                 + s[S_AW1+i*6+2]*m2 + s[S_AW1+i*6+3]*m3
                 + s[S_AW1+i*6+4]*m4 + s[S_AW1+i*6+5]*m5;
        ha = ftanh(ha);
        ac0 += s[S_AW2+i]*ha; ac1 += s[S_AW2+32+i]*ha; ac2 += s[S_AW2+64+i]*ha;
    }
    float u0 = s[S_UB2+0], u1 = s[S_UB2+1], u2 = s[S_UB2+2];
    float u3 = s[S_UB2+3], u4 = s[S_UB2+4], u5 = s[S_UB2+5];
    #pragma unroll
    for (int i = 0; i < 16; ++i) {
        float hu = s[S_UB1+i] + s[S_UW1+i*6+0]*m0 + s[S_UW1+i*6+1]*m1
                 + s[S_UW1+i*6+2]*m2 + s[S_UW1+i*6+3]*m3
                 + s[S_UW1+i*6+4]*m4 + s[S_UW1+i*6+5]*m5;
        hu = fmaxf(hu, 0.f);
        u0 += s[S_UW2+i]*hu;      u1 += s[S_UW2+16+i]*hu; u2 += s[S_UW2+32+i]*hu;
        u3 += s[S_UW2+48+i]*hu;   u4 += s[S_UW2+64+i]*hu; u5 += s[S_UW2+80+i]*hu;
    }
    out[base+0] = gy0; out[base+1] = gy1; out[base+2] = gy2;
    out[base+3] = ac0; out[base+4] = ac1; out[base+5] = ac2;
    const long uoff = (long)BATCH * TSTEPS * 6;
    out[uoff+base+0] = fsoftplus(u0); out[uoff+base+1] = fsoftplus(u1);
    out[uoff+base+2] = fsoftplus(u2); out[uoff+base+3] = fsoftplus(u3);
    out[uoff+base+4] = fsoftplus(u4); out[uoff+base+5] = fsoftplus(u5);
}

extern "C" void kernel_launch(void* const* d_in, const int* in_sizes, int n_in,
                              void* d_out, int out_size, void* d_ws, size_t ws_size,
                              hipStream_t stream) {
    const float* x       = (const float*)d_in[0];
    const float* lstm_wi = (const float*)d_in[1];
    const float* lstm_wh = (const float*)d_in[2];
    const float* lstm_b  = (const float*)d_in[3];
    const float* c0w1 = (const float*)d_in[4];
    const float* c0w2 = (const float*)d_in[5];
    const float* c0wa = (const float*)d_in[6];
    const float* c0wb = (const float*)d_in[7];
    const float* c0b1 = (const float*)d_in[8];
    const float* c0b2 = (const float*)d_in[9];
    const float* c0ba = (const float*)d_in[10];
    const float* c0bb = (const float*)d_in[11];
    const float* c1w1 = (const float*)d_in[12];
    const float* c1w2 = (const float*)d_in[13];
    const float* c1wa = (const float*)d_in[14];
    const float* c1wb = (const float*)d_in[15];
    const float* c1b1 = (const float*)d_in[16];
    const float* c1b2 = (const float*)d_in[17];
    const float* c1ba = (const float*)d_in[18];
    const float* c1bb = (const float*)d_in[19];
    const float* c2w1 = (const float*)d_in[20];
    const float* c2w2 = (const float*)d_in[21];
    const float* c2wa = (const float*)d_in[22];
    const float* c2wb = (const float*)d_in[23];
    const float* c2b1 = (const float*)d_in[24];
    const float* c2b2 = (const float*)d_in[25];
    const float* c2ba = (const float*)d_in[26];
    const float* c2bb = (const float*)d_in[27];
    const float* gw1 = (const float*)d_in[28];
    const float* gb1 = (const float*)d_in[29];
    const float* gw2 = (const float*)d_in[30];
    const float* gb2 = (const float*)d_in[31];
    const float* aw1 = (const float*)d_in[32];
    const float* ab1 = (const float*)d_in[33];
    const float* aw2 = (const float*)d_in[34];
    const float* ab2 = (const float*)d_in[35];
    const float* uw1 = (const float*)d_in[36];
    const float* ub1 = (const float*)d_in[37];
    const float* uw2 = (const float*)d_in[38];
    const float* ub2 = (const float*)d_in[39];
    float* out = (float*)d_out;

    rnn_kernel<<<BATCH, 512, 0, stream>>>(x, lstm_wi, lstm_wh, lstm_b,
        c0w1, c0w2, c0wa, c0wb, c0b1, c0b2, c0ba, c0bb,
        c1w1, c1w2, c1wa, c1wb, c1b1, c1b2, c1ba, c1bb,
        c2w1, c2w2, c2wa, c2wb, c2b1, c2b2, c2ba, c2bb, out);

    head_kernel<<<(BATCH * TSTEPS) / 256, 256, 0, stream>>>(
        gw1, gb1, gw2, gb2, aw1, ab1, aw2, ab2, uw1, ub1, uw2, ub2, out);
}

// Round 8
// 6384.888 us; speedup vs baseline: 1.0684x; 1.0684x over previous
//
#include <hip/hip_runtime.h>
#include <math.h>

#define BATCH 128
#define TSTEPS 4096
#define INDIM 13

// LDS layout (256 floats, fully zero-initialized each launch):
//  zL[0:96]  = smem+0    [x(13) | o0(35) | o1(23) | o2(6) | pad(19)] LSTM input
//  z0[0:64]  = smem+96   [x(13) | h0_lstm(35) | pad(16)]             CfC0 input
//  z1[0:64]  = smem+160  [o0(35) | h1_lstm(23) | pad(6)]             CfC1 input
//  z2[0:32]  = smem+224  [o1(23) | h2_lstm(6) | pad(3)]              CfC2 input
//
// Phase skeleton per step (4 barriers), with the LSTM main dot HOISTED into
// phase 4 of the previous step (cols 0..68 of zL are known after P3: x_{t+1}
// committed in P3, o0 in P2, o1 in P3). Phase 1 only adds the o2 leftover
// (cols 68..80), reduces, and does the cell update.

__device__ __forceinline__ float fsig(float x) {
    return __builtin_amdgcn_rcpf(1.f + __expf(-x));
}
__device__ __forceinline__ float ftanh(float x) {
    float s = fsig(x + x);
    return s + s - 1.f;
}
__device__ __forceinline__ float fsoftplus(float x) {
    return (x > 15.f) ? x : __logf(1.f + __expf(x));
}

// lane exchanges via DPP only (VALU latency; no LDS pipe in the reduce)
__device__ __forceinline__ float qxor1(float v) {   // quad_perm [1,0,3,2]
    return __int_as_float(__builtin_amdgcn_update_dpp(
        0, __float_as_int(v), 0xB1, 0xF, 0xF, true));
}
__device__ __forceinline__ float qxor2(float v) {   // quad_perm [2,3,0,1]
    return __int_as_float(__builtin_amdgcn_update_dpp(
        0, __float_as_int(v), 0x4E, 0xF, 0xF, true));
}
__device__ __forceinline__ float hmir(float v) {    // row_half_mirror (8-lane)
    return __int_as_float(__builtin_amdgcn_update_dpp(
        0, __float_as_int(v), 0x141, 0xF, 0xF, true));
}
// 8-lane butterfly allreduce, all-DPP, bit-identical on all 8 lanes.
#define BFLY8(a) { a += qxor1(a); a += qxor2(a); a += hmir(a); }

// acc += dot(float4 zv, 4 named weight scalars W_q_{0..3})
#define FMA4(acc, W, q, zv) { acc += zv.x * W##_##q##_0; acc += zv.y * W##_##q##_1; \
                              acc += zv.z * W##_##q##_2; acc += zv.w * W##_##q##_3; }

// LSTM partial over this lane's float4s that lie fully below col 68
// (k<5: cols 12k..12k+12; k==5: cols 60..68; k>=6: nothing).
#define LPART() { \
    p0 = 0.f; p1 = 0.f; p2 = 0.f; p3 = 0.f; \
    if (k < 5) { \
        const float4* zc = (const float4*)(zL + 12 * k); \
        float4 q0 = zc[0], q1 = zc[1], q2 = zc[2]; \
        FMA4(p0, wl0, 0, q0) FMA4(p0, wl0, 1, q1) FMA4(p0, wl0, 2, q2) \
        FMA4(p1, wl1, 0, q0) FMA4(p1, wl1, 1, q1) FMA4(p1, wl1, 2, q2) \
        FMA4(p2, wl2, 0, q0) FMA4(p2, wl2, 1, q1) FMA4(p2, wl2, 2, q2) \
        FMA4(p3, wl3, 0, q0) FMA4(p3, wl3, 1, q1) FMA4(p3, wl3, 2, q2) \
    } else if (k == 5) { \
        const float4* zc = (const float4*)(zL + 60); \
        float4 q0 = zc[0], q1 = zc[1]; \
        FMA4(p0, wl0, 0, q0) FMA4(p0, wl0, 1, q1) \
        FMA4(p1, wl1, 0, q0) FMA4(p1, wl1, 1, q1) \
        FMA4(p2, wl2, 0, q0) FMA4(p2, wl2, 1, q1) \
        FMA4(p3, wl3, 0, q0) FMA4(p3, wl3, 1, q1) \
    } }

__global__ __launch_bounds__(512, 2)
void rnn_kernel(const float* __restrict__ x,
                const float* __restrict__ lstm_wi, const float* __restrict__ lstm_wh,
                const float* __restrict__ lstm_b,
                const float* __restrict__ c0w1, const float* __restrict__ c0w2,
                const float* __restrict__ c0wa, const float* __restrict__ c0wb,
                const float* __restrict__ c0b1, const float* __restrict__ c0b2,
                const float* __restrict__ c0ba, const float* __restrict__ c0bb,
                const float* __restrict__ c1w1, const float* __restrict__ c1w2,
                const float* __restrict__ c1wa, const float* __restrict__ c1wb,
                const float* __restrict__ c1b1, const float* __restrict__ c1b2,
                const float* __restrict__ c1ba, const float* __restrict__ c1bb,
                const float* __restrict__ c2w1, const float* __restrict__ c2w2,
                const float* __restrict__ c2wa, const float* __restrict__ c2wb,
                const float* __restrict__ c2b1, const float* __restrict__ c2b2,
                const float* __restrict__ c2ba, const float* __restrict__ c2bb,
                float* __restrict__ out)
{
    const int bb = blockIdx.x;
    const int t  = threadIdx.x;     // 0..511
    const int k  = t & 7;           // K-chunk slot within the octet
    const int u  = t >> 3;          // unit / row-group index 0..63

    __shared__ __align__(16) float smem[256];
    float* zL = smem;
    float* z0 = smem + 96;
    float* z1 = smem + 160;
    float* z2 = smem + 224;

    const long xbase = (long)bb * TSTEPS * INDIM;
    const long obase = (long)bb * TSTEPS * 6;

    // ---- LSTM weights: lane (u,k) holds cols [12k,12k+12) of all 4 gate rows
    auto lwf = [&](int A, int c) -> float {
        int r = A * 64 + u;
        return (c < 13) ? lstm_wi[r * 13 + c]
             : (c < 77) ? lstm_wh[r * 64 + (c - 13)] : 0.f;
    };
#define DEF_WL(A,q) \
    float wl##A##_##q##_0 = lwf(A, 12*k + 4*q + 0); \
    float wl##A##_##q##_1 = lwf(A, 12*k + 4*q + 1); \
    float wl##A##_##q##_2 = lwf(A, 12*k + 4*q + 2); \
    float wl##A##_##q##_3 = lwf(A, 12*k + 4*q + 3);
    DEF_WL(0,0) DEF_WL(0,1) DEF_WL(0,2)
    DEF_WL(1,0) DEF_WL(1,1) DEF_WL(1,2)
    DEF_WL(2,0) DEF_WL(2,1) DEF_WL(2,2)
    DEF_WL(3,0) DEF_WL(3,1) DEF_WL(3,2)
#undef DEF_WL
    const float bL0 = lstm_b[u];
    const float bL1 = lstm_b[64 + u];
    const float bL2 = lstm_b[128 + u];
    const float bL3 = lstm_b[192 + u];

    // ---- CfC weights: octet groups (disjoint lane sets, one name overlay)
    const int grp  = (u < 35) ? 0 : (u < 58) ? 1 : 2;
    const int row  = (grp == 0) ? u : (grp == 1) ? (u - 35) : (u - 58);
    const int rl   = (grp == 0) ? 48 : (grp == 1) ? 58 : 29;
    const int clen = (grp == 2) ? 4 : 8;
    const int cb   = (grp == 2) ? 4 * k : 8 * k;
    const float *W0p, *W1p, *W2p, *W3p;
    float bC0, bC1, bC2, bC3;
    if (grp == 0) {
        W0p = c0w1 + row * 48; W1p = c0w2 + row * 48;
        W2p = c0wa + row * 48; W3p = c0wb + row * 48;
        bC0 = c0b1[row]; bC1 = c0b2[row]; bC2 = c0ba[row]; bC3 = c0bb[row];
    } else if (grp == 1) {
        W0p = c1w1 + row * 58; W1p = c1w2 + row * 58;
        W2p = c1wa + row * 58; W3p = c1wb + row * 58;
        bC0 = c1b1[row]; bC1 = c1b2[row]; bC2 = c1ba[row]; bC3 = c1bb[row];
    } else {
        W0p = c2w1 + row * 29; W1p = c2w2 + row * 29;
        W2p = c2wa + row * 29; W3p = c2wb + row * 29;
        bC0 = c2b1[row]; bC1 = c2b2[row]; bC2 = c2ba[row]; bC3 = c2bb[row];
    }
    auto cwf = [&](const float* W, int c) -> float {
        int cc = cb + c;
        return (c < clen && cc < rl) ? W[cc] : 0.f;
    };
#define DEF_WC(A,q) \
    float wc##A##_##q##_0 = cwf(W##A##p, 4*q + 0); \
    float wc##A##_##q##_1 = cwf(W##A##p, 4*q + 1); \
    float wc##A##_##q##_2 = cwf(W##A##p, 4*q + 2); \
    float wc##A##_##q##_3 = cwf(W##A##p, 4*q + 3);
    DEF_WC(0,0) DEF_WC(0,1)
    DEF_WC(1,0) DEF_WC(1,1)
    DEF_WC(2,0) DEF_WC(2,1)
    DEF_WC(3,0) DEF_WC(3,1)
#undef DEF_WC

    // lane duties (all in otherwise-idle slots; grp1 lanes idle in P2):
    const bool cpx = (t >= 256 && t < 269);  // z0 x-copy in P1 (grp0 waves)
    const bool stl = (t >= 320 && t < 326);  // out-store at top of P2 (u=40, grp1)
    const bool pfl = (t >= 328 && t < 341);  // x prefetch: issue P2, commit P3 (grp1)

    float creg = 0.f;                         // cell state, replicated per octet

    // ---- init LDS: zero everything, then x_0 ----
    if (t < 256) smem[t] = 0.f;
    __syncthreads();
    if (t < 13) zL[t] = x[xbase + t];
    __syncthreads();

    // prime LSTM partials for step 0 (zL = [x_0 | zeros])
    float p0, p1, p2, p3;
    LPART();

    #pragma unroll 1
    for (int ts = 0; ts < TSTEPS; ++ts) {
        // ---- phase 1: finish LSTM (leftover o2 cols 68..80) + cell update ----
        {
            float a0 = p0, a1 = p1, a2 = p2, a3 = p3;
            if (k == 5) {
                float4 v = *(const float4*)(zL + 68);
                FMA4(a0, wl0, 2, v) FMA4(a1, wl1, 2, v)
                FMA4(a2, wl2, 2, v) FMA4(a3, wl3, 2, v)
            } else if (k == 6) {
                const float4* zc = (const float4*)(zL + 72);
                float4 v0 = zc[0], v1 = zc[1];
                FMA4(a0, wl0, 0, v0) FMA4(a0, wl0, 1, v1)
                FMA4(a1, wl1, 0, v0) FMA4(a1, wl1, 1, v1)
                FMA4(a2, wl2, 0, v0) FMA4(a2, wl2, 1, v1)
                FMA4(a3, wl3, 0, v0) FMA4(a3, wl3, 1, v1)
            }
            BFLY8(a0) BFLY8(a1) BFLY8(a2) BFLY8(a3)
            a0 += bL0; a1 += bL1; a2 += bL2; a3 += bL3;   // ia, ig, fg, og
            float cn = creg * fsig(a2 + 1.f) + ftanh(a0) * fsig(a1);
            creg = cn;                      // bit-identical on all 8 octet lanes
            float hl = ftanh(cn) * fsig(a3);
            if (k == 0) {
                if (u < 35)      z0[13 + u] = hl;   // h0
                else if (u < 58) z1[u]      = hl;   // h1 at z1[35..57]
                else             z2[u - 35] = hl;   // h2 at z2[23..28]
            }
            if (cpx) z0[t - 256] = zL[t - 256];     // x_t -> CfC0 input
        }
        __syncthreads();

        // ---- phase 2: CfC0 (grp0) + out-store(ts-1) + x-prefetch issue ----
        float xn = 0.f;
        if (pfl && (ts + 1) < TSTEPS)
            xn = x[xbase + (long)(ts + 1) * 13 + (t - 328)];
        if (stl && ts > 0)
            out[obase + (long)(ts - 1) * 6 + (t - 320)] = zL[71 + (t - 320)];
        if (grp == 0) {
            const float4* zc = (const float4*)(z0 + 8 * k);
            float4 v0 = zc[0], v1 = zc[1];
            float a0 = 0.f, a1 = 0.f, a2 = 0.f, a3 = 0.f;
            FMA4(a0, wc0, 0, v0) FMA4(a0, wc0, 1, v1)
            FMA4(a1, wc1, 0, v0) FMA4(a1, wc1, 1, v1)
            FMA4(a2, wc2, 0, v0) FMA4(a2, wc2, 1, v1)
            FMA4(a3, wc3, 0, v0) FMA4(a3, wc3, 1, v1)
            BFLY8(a0) BFLY8(a1) BFLY8(a2) BFLY8(a3)
            a0 += bC0; a1 += bC1; a2 += bC2; a3 += bC3;
            float tg = fsig(a2 + a3);
            float f1 = ftanh(a0), f2 = ftanh(a1);
            float o = f1 + tg * (f2 - f1);
            if (k == 0) { z1[row] = o; zL[13 + row] = o; }
        }
        __syncthreads();

        // ---- phase 3: CfC1 (grp1) + x_{t+1} commit into zL[0:13) ----
        if (pfl) zL[t - 328] = xn;
        if (grp == 1) {
            const float4* zc = (const float4*)(z1 + 8 * k);
            float4 v0 = zc[0], v1 = zc[1];
            float a0 = 0.f, a1 = 0.f, a2 = 0.f, a3 = 0.f;
            FMA4(a0, wc0, 0, v0) FMA4(a0, wc0, 1, v1)
            FMA4(a1, wc1, 0, v0) FMA4(a1, wc1, 1, v1)
            FMA4(a2, wc2, 0, v0) FMA4(a2, wc2, 1, v1)
            FMA4(a3, wc3, 0, v0) FMA4(a3, wc3, 1, v1)
            BFLY8(a0) BFLY8(a1) BFLY8(a2) BFLY8(a3)
            a0 += bC0; a1 += bC1; a2 += bC2; a3 += bC3;
            float tg = fsig(a2 + a3);
            float f1 = ftanh(a0), f2 = ftanh(a1);
            float o = f1 + tg * (f2 - f1);
            if (k == 0) { z2[row] = o; zL[48 + row] = o; }
        }
        __syncthreads();

        // ---- phase 4: CfC2 (grp2) || LSTM main partial for step ts+1 ----
        // zL cols 0..68 = [x_{t+1} | o0 | o1] all final; grp2 writes zL[71..77]
        // (disjoint). All 512 lanes recompute p0..p3 here.
        if (grp == 2) {
            const float4* zc = (const float4*)(z2 + 4 * k);
            float4 v0 = zc[0];
            float a0 = 0.f, a1 = 0.f, a2 = 0.f, a3 = 0.f;
            FMA4(a0, wc0, 0, v0)
            FMA4(a1, wc1, 0, v0)
            FMA4(a2, wc2, 0, v0)
            FMA4(a3, wc3, 0, v0)
            BFLY8(a0) BFLY8(a1) BFLY8(a2) BFLY8(a3)
            a0 += bC0; a1 += bC1; a2 += bC2; a3 += bC3;
            float tg = fsig(a2 + a3);
            float f1 = ftanh(a0), f2 = ftanh(a1);
            float o = f1 + tg * (f2 - f1);
            if (k == 0) zL[71 + row] = o;   // o2 -> LDS only; stored next step
        }
        LPART();
        __syncthreads();
    }

    // epilogue: store the last step's motor output
    if (t < 6) out[obase + (long)(TSTEPS - 1) * 6 + t] = zL[71 + t];
}

// ---- head: rewrite pred in place, write unc ----
#define S_GW1 0
#define S_GB1 192
#define S_GW2 224
#define S_GB2 320
#define S_AW1 323
#define S_AB1 515
#define S_AW2 547
#define S_AB2 643
#define S_UW1 646
#define S_UB1 742
#define S_UW2 758
#define S_UB2 854
#define S_TOT 860

__global__ __launch_bounds__(256)
void head_kernel(const float* __restrict__ gw1, const float* __restrict__ gb1,
                 const float* __restrict__ gw2, const float* __restrict__ gb2,
                 const float* __restrict__ aw1, const float* __restrict__ ab1,
                 const float* __restrict__ aw2, const float* __restrict__ ab2,
                 const float* __restrict__ uw1, const float* __restrict__ ub1,
                 const float* __restrict__ uw2, const float* __restrict__ ub2,
                 float* __restrict__ out)
{
    __shared__ float s[S_TOT];
    const int t = threadIdx.x;
    if (t < 192) { s[S_GW1 + t] = gw1[t]; s[S_AW1 + t] = aw1[t]; }
    if (t < 96)  { s[S_GW2 + t] = gw2[t]; s[S_AW2 + t] = aw2[t];
                   s[S_UW1 + t] = uw1[t]; s[S_UW2 + t] = uw2[t]; }
    if (t < 32)  { s[S_GB1 + t] = gb1[t]; s[S_AB1 + t] = ab1[t]; }
    if (t < 16)  { s[S_UB1 + t] = ub1[t]; }
    if (t < 3)   { s[S_GB2 + t] = gb2[t]; s[S_AB2 + t] = ab2[t]; }
    if (t < 6)   { s[S_UB2 + t] = ub2[t]; }
    __syncthreads();

    const long p = (long)blockIdx.x * 256 + t;   // < B*T exactly
    const long base = p * 6;
    float m0 = out[base+0], m1 = out[base+1], m2 = out[base+2];
    float m3 = out[base+3], m4 = out[base+4], m5 = out[base+5];

    float gy0 = s[S_GB2+0], gy1 = s[S_GB2+1], gy2 = s[S_GB2+2];
    float ac0 = s[S_AB2+0], ac1 = s[S_AB2+1], ac2 = s[S_AB2+2];
    #pragma unroll
    for (int i = 0; i < 32; ++i) {
        float hg = s[S_GB1+i] + s[S_GW1+i*6+0]*m0 + s[S_GW1+i*6+1]*m1
                 + s[S_GW1+i*6+2]*m2 + s[S_GW1+i*6+3]*m3
                 + s[S_GW1+i*6+4]*m4 + s[S_GW1+i*6+5]*m5;
        hg = ftanh(hg);
        gy0 += s[S_GW2+i]*hg; gy1 += s[S_GW2+32+i]*hg; gy2 += s[S_GW2+64+i]*hg;
        float ha = s[S_AB1+i] + s[S_AW1+i*6+0]*m0 + s[S_AW1+i*6+1]*m1
                 + s[S_AW1+i*6+2]*m2 + s[S_AW1+i*6+3]*m3
                 + s[S_AW1+i*6+4]*m4 + s[S_AW1+i*6+5]*m5;
        ha = ftanh(ha);
        ac0 += s[S_AW2+i]*ha; ac1 += s[S_AW2+32+i]*ha; ac2 += s[S_AW2+64+i]*ha;
    }
    float u0 = s[S_UB2+0], u1 = s[S_UB2+1], u2 = s[S_UB2+2];
    float u3 = s[S_UB2+3], u4 = s[S_UB2+4], u5 = s[S_UB2+5];
    #pragma unroll
    for (int i = 0; i < 16; ++i) {
        float hu = s[S_UB1+i] + s[S_UW1+i*6+0]*m0 + s[S_UW1+i*6+1]*m1
                 + s[S_UW1+i*6+2]*m2 + s[S_UW1+i*6+3]*m3
                 + s[S_UW1+i*6+4]*m4 + s[S_UW1+i*6+5]*m5;
        hu = fmaxf(hu, 0.f);
        u0 += s[S_UW2+i]*hu;      u1 += s[S_UW2+16+i]*hu; u2 += s[S_UW2+32+i]*hu;
        u3 += s[S_UW2+48+i]*hu;   u4 += s[S_UW2+64+i]*hu; u5 += s[S_UW2+80+i]*hu;
    }
    out[base+0] = gy0; out[base+1] = gy1; out[base+2] = gy2;
    out[base+3] = ac0; out[base+4] = ac1; out[base+5] = ac2;
    const long uoff = (long)BATCH * TSTEPS * 6;
    out[uoff+base+0] = fsoftplus(u0); out[uoff+base+1] = fsoftplus(u1);
    out[uoff+base+2] = fsoftplus(u2); out[uoff+base+3] = fsoftplus(u3);
    out[uoff+base+4] = fsoftplus(u4); out[uoff+base+5] = fsoftplus(u5);
}

extern "C" void kernel_launch(void* const* d_in, const int* in_sizes, int n_in,
                              void* d_out, int out_size, void* d_ws, size_t ws_size,
                              hipStream_t stream) {
    const float* x       = (const float*)d_in[0];
    const float* lstm_wi = (const float*)d_in[1];
    const float* lstm_wh = (const float*)d_in[2];
    const float* lstm_b  = (const float*)d_in[3];
    const float* c0w1 = (const float*)d_in[4];
    const float* c0w2 = (const float*)d_in[5];
    const float* c0wa = (const float*)d_in[6];
    const float* c0wb = (const float*)d_in[7];
    const float* c0b1 = (const float*)d_in[8];
    const float* c0b2 = (const float*)d_in[9];
    const float* c0ba = (const float*)d_in[10];
    const float* c0bb = (const float*)d_in[11];
    const float* c1w1 = (const float*)d_in[12];
    const float* c1w2 = (const float*)d_in[13];
    const float* c1wa = (const float*)d_in[14];
    const float* c1wb = (const float*)d_in[15];
    const float* c1b1 = (const float*)d_in[16];
    const float* c1b2 = (const float*)d_in[17];
    const float* c1ba = (const float*)d_in[18];
    const float* c1bb = (const float*)d_in[19];
    const float* c2w1 = (const float*)d_in[20];
    const float* c2w2 = (const float*)d_in[21];
    const float* c2wa = (const float*)d_in[22];
    const float* c2wb = (const float*)d_in[23];
    const float* c2b1 = (const float*)d_in[24];
    const float* c2b2 = (const float*)d_in[25];
    const float* c2ba = (const float*)d_in[26];
    const float* c2bb = (const float*)d_in[27];
    const float* gw1 = (const float*)d_in[28];
    const float* gb1 = (const float*)d_in[29];
    const float* gw2 = (const float*)d_in[30];
    const float* gb2 = (const float*)d_in[31];
    const float* aw1 = (const float*)d_in[32];
    const float* ab1 = (const float*)d_in[33];
    const float* aw2 = (const float*)d_in[34];
    const float* ab2 = (const float*)d_in[35];
    const float* uw1 = (const float*)d_in[36];
    const float* ub1 = (const float*)d_in[37];
    const float* uw2 = (const float*)d_in[38];
    const float* ub2 = (const float*)d_in[39];
    float* out = (float*)d_out;

    rnn_kernel<<<BATCH, 512, 0, stream>>>(x, lstm_wi, lstm_wh, lstm_b,
        c0w1, c0w2, c0wa, c0wb, c0b1, c0b2, c0ba, c0bb,
        c1w1, c1w2, c1wa, c1wb, c1b1, c1b2, c1ba, c1bb,
        c2w1, c2w2, c2wa, c2wb, c2b1, c2b2, c2ba, c2bb, out);

    head_kernel<<<(BATCH * TSTEPS) / 256, 256, 0, stream>>>(
        gw1, gb1, gw2, gb2, aw1, ab1, aw2, ab2, uw1, ub1, uw2, ub2, out);
}

// Round 9
// 5452.978 us; speedup vs baseline: 1.2510x; 1.1709x over previous
//
#include <hip/hip_runtime.h>
#include <math.h>

#define BATCH 128
#define TSTEPS 4096
#define INDIM 13
#define XT 64   // steps per x/out LDS tile

// LDS layout (floats):
//  state[0:256):  zL[0:96) | z0 @96 | z1 @160 | z2 @224   (zero-initialized)
//  xt0 @256 (832) | xt1 @1088 (832)   x tiles, double-buffered (64 steps x 13)
//  ot0 @1920 (384) | ot1 @2304 (384)  out tiles, double-buffered (64 steps x 6)
// Steady-state loop has NO global-memory instructions -> barriers drain
// lgkmcnt only (the compiler's vmcnt(0)-before-s_barrier drain cost is paid
// twice per 64 steps instead of twice per step).

__device__ __forceinline__ float fsig(float x) {
    return __builtin_amdgcn_rcpf(1.f + __expf(-x));
}
__device__ __forceinline__ float ftanh(float x) {
    float s = fsig(x + x);
    return s + s - 1.f;
}
__device__ __forceinline__ float fsoftplus(float x) {
    return (x > 15.f) ? x : __logf(1.f + __expf(x));
}

// lane exchanges via DPP only (VALU latency; no LDS pipe in the reduce)
__device__ __forceinline__ float qxor1(float v) {   // quad_perm [1,0,3,2]
    return __int_as_float(__builtin_amdgcn_update_dpp(
        0, __float_as_int(v), 0xB1, 0xF, 0xF, true));
}
__device__ __forceinline__ float qxor2(float v) {   // quad_perm [2,3,0,1]
    return __int_as_float(__builtin_amdgcn_update_dpp(
        0, __float_as_int(v), 0x4E, 0xF, 0xF, true));
}
__device__ __forceinline__ float hmir(float v) {    // row_half_mirror (8-lane)
    return __int_as_float(__builtin_amdgcn_update_dpp(
        0, __float_as_int(v), 0x141, 0xF, 0xF, true));
}
// 8-lane butterfly allreduce, all-DPP, bit-identical on all 8 lanes
// (verified rounds 7/8: after quad reduce both quads are uniform; half-mirror
// adds the other quad's uniform sum; float add is bitwise commutative).
#define BFLY8(a) { a += qxor1(a); a += qxor2(a); a += hmir(a); }

// acc += dot(float4 zv, 4 named weight scalars W_q_{0..3})
#define FMA4(acc, W, q, zv) { acc += zv.x * W##_##q##_0; acc += zv.y * W##_##q##_1; \
                              acc += zv.z * W##_##q##_2; acc += zv.w * W##_##q##_3; }

__global__ __launch_bounds__(512, 2)
void rnn_kernel(const float* __restrict__ x,
                const float* __restrict__ lstm_wi, const float* __restrict__ lstm_wh,
                const float* __restrict__ lstm_b,
                const float* __restrict__ c0w1, const float* __restrict__ c0w2,
                const float* __restrict__ c0wa, const float* __restrict__ c0wb,
                const float* __restrict__ c0b1, const float* __restrict__ c0b2,
                const float* __restrict__ c0ba, const float* __restrict__ c0bb,
                const float* __restrict__ c1w1, const float* __restrict__ c1w2,
                const float* __restrict__ c1wa, const float* __restrict__ c1wb,
                const float* __restrict__ c1b1, const float* __restrict__ c1b2,
                const float* __restrict__ c1ba, const float* __restrict__ c1bb,
                const float* __restrict__ c2w1, const float* __restrict__ c2w2,
                const float* __restrict__ c2wa, const float* __restrict__ c2wb,
                const float* __restrict__ c2b1, const float* __restrict__ c2b2,
                const float* __restrict__ c2ba, const float* __restrict__ c2bb,
                float* __restrict__ out)
{
    const int bb = blockIdx.x;
    const int t  = threadIdx.x;     // 0..511
    const int k  = t & 7;           // K-chunk slot within the octet
    const int u  = t >> 3;          // unit / row-group index 0..63

    __shared__ __align__(16) float smem[2688];
    float* zL  = smem;
    float* z0  = smem + 96;
    float* z1  = smem + 160;
    float* z2  = smem + 224;
    float* xt0 = smem + 256;
    float* xt1 = smem + 1088;
    float* ot0 = smem + 1920;
    float* ot1 = smem + 2304;

    const long xbase = (long)bb * TSTEPS * INDIM;
    const long obase = (long)bb * TSTEPS * 6;

    // ---- LSTM weights: lane (u,k) holds cols [12k,12k+12) of all 4 gate rows
    auto lwf = [&](int A, int c) -> float {
        int r = A * 64 + u;
        return (c < 13) ? lstm_wi[r * 13 + c]
             : (c < 77) ? lstm_wh[r * 64 + (c - 13)] : 0.f;
    };
#define DEF_WL(A,q) \
    float wl##A##_##q##_0 = lwf(A, 12*k + 4*q + 0); \
    float wl##A##_##q##_1 = lwf(A, 12*k + 4*q + 1); \
    float wl##A##_##q##_2 = lwf(A, 12*k + 4*q + 2); \
    float wl##A##_##q##_3 = lwf(A, 12*k + 4*q + 3);
    DEF_WL(0,0) DEF_WL(0,1) DEF_WL(0,2)
    DEF_WL(1,0) DEF_WL(1,1) DEF_WL(1,2)
    DEF_WL(2,0) DEF_WL(2,1) DEF_WL(2,2)
    DEF_WL(3,0) DEF_WL(3,1) DEF_WL(3,2)
#undef DEF_WL
    const float bL0 = lstm_b[u];
    const float bL1 = lstm_b[64 + u];
    const float bL2 = lstm_b[128 + u];
    const float bL3 = lstm_b[192 + u];

    // ---- CfC weights: octet groups (disjoint lane sets, one name overlay)
    // grp0 (u<35, lanes 0..279):   row u,    len 48, chunk 8 at 8k
    // grp1 (u<58, lanes 280..463): row u-35, len 58, chunk 8 at 8k
    // grp2 (u>=58, lanes 464..511):row u-58, len 29, chunk 4 at 4k
    const int grp  = (u < 35) ? 0 : (u < 58) ? 1 : 2;
    const int row  = (grp == 0) ? u : (grp == 1) ? (u - 35) : (u - 58);
    const int rl   = (grp == 0) ? 48 : (grp == 1) ? 58 : 29;
    const int clen = (grp == 2) ? 4 : 8;
    const int cb   = (grp == 2) ? 4 * k : 8 * k;
    const float *W0p, *W1p, *W2p, *W3p;
    float bC0, bC1, bC2, bC3;
    if (grp == 0) {
        W0p = c0w1 + row * 48; W1p = c0w2 + row * 48;
        W2p = c0wa + row * 48; W3p = c0wb + row * 48;
        bC0 = c0b1[row]; bC1 = c0b2[row]; bC2 = c0ba[row]; bC3 = c0bb[row];
    } else if (grp == 1) {
        W0p = c1w1 + row * 58; W1p = c1w2 + row * 58;
        W2p = c1wa + row * 58; W3p = c1wb + row * 58;
        bC0 = c1b1[row]; bC1 = c1b2[row]; bC2 = c1ba[row]; bC3 = c1bb[row];
    } else {
        W0p = c2w1 + row * 29; W1p = c2w2 + row * 29;
        W2p = c2wa + row * 29; W3p = c2wb + row * 29;
        bC0 = c2b1[row]; bC1 = c2b2[row]; bC2 = c2ba[row]; bC3 = c2bb[row];
    }
    auto cwf = [&](const float* W, int c) -> float {
        int cc = cb + c;
        return (c < clen && cc < rl) ? W[cc] : 0.f;
    };
#define DEF_WC(A,q) \
    float wc##A##_##q##_0 = cwf(W##A##p, 4*q + 0); \
    float wc##A##_##q##_1 = cwf(W##A##p, 4*q + 1); \
    float wc##A##_##q##_2 = cwf(W##A##p, 4*q + 2); \
    float wc##A##_##q##_3 = cwf(W##A##p, 4*q + 3);
    DEF_WC(0,0) DEF_WC(0,1)
    DEF_WC(1,0) DEF_WC(1,1)
    DEF_WC(2,0) DEF_WC(2,1)
    DEF_WC(3,0) DEF_WC(3,1)
#undef DEF_WC

    float creg = 0.f;                         // cell state, replicated per octet

    // ---- prologue: zero state, load x tile 0, seed x_0 ----
    if (t < 256) smem[t] = 0.f;
    if (t < 208) {                            // 208 float4 = 64 steps x 13
        float4 xi = *(const float4*)(x + xbase + 4 * t);
        *(float4*)&xt0[4 * t] = xi;
    }
    if (t < 13) zL[t] = x[xbase + t];
    __syncthreads();

    #pragma unroll 1
    for (int ts = 0; ts < TSTEPS; ++ts) {
        const int par = (ts >> 6) & 1;
        const int lts = ts & 63;

        // ---- phase 1: LSTM (all 512 lanes; K-split by k) ----
        if (t >= 256 && t < 269) z0[t - 256] = zL[t - 256];  // x_t -> CfC0 input
        {
            const float4* zc = (const float4*)(zL + 12 * k);
            float4 q0 = zc[0], q1 = zc[1], q2 = zc[2];
            float a0 = 0.f, a1 = 0.f, a2 = 0.f, a3 = 0.f;
            FMA4(a0, wl0, 0, q0) FMA4(a0, wl0, 1, q1) FMA4(a0, wl0, 2, q2)
            FMA4(a1, wl1, 0, q0) FMA4(a1, wl1, 1, q1) FMA4(a1, wl1, 2, q2)
            FMA4(a2, wl2, 0, q0) FMA4(a2, wl2, 1, q1) FMA4(a2, wl2, 2, q2)
            FMA4(a3, wl3, 0, q0) FMA4(a3, wl3, 1, q1) FMA4(a3, wl3, 2, q2)
            BFLY8(a0) BFLY8(a1) BFLY8(a2) BFLY8(a3)
            a0 += bL0; a1 += bL1; a2 += bL2; a3 += bL3;   // ia, ig, fg, og
            float cn = creg * fsig(a2 + 1.f) + ftanh(a0) * fsig(a1);
            creg = cn;                      // bit-identical on all 8 octet lanes
            float hl = ftanh(cn) * fsig(a3);
            if (k == 0) {
                if (u < 35)      z0[13 + u] = hl;   // h0
                else if (u < 58) z1[u]      = hl;   // h1 at z1[35..57]
                else             z2[u - 35] = hl;   // h2 at z2[23..28]
            }
        }
        __syncthreads();

        // ---- phase 2: CfC0 (lanes 0..279) || tile refill / out flush ----
        if (grp == 0) {
            const float4* zc = (const float4*)(z0 + 8 * k);
            float4 v0 = zc[0], v1 = zc[1];
            float a0 = 0.f, a1 = 0.f, a2 = 0.f, a3 = 0.f;
            FMA4(a0, wc0, 0, v0) FMA4(a0, wc0, 1, v1)
            FMA4(a1, wc1, 0, v0) FMA4(a1, wc1, 1, v1)
            FMA4(a2, wc2, 0, v0) FMA4(a2, wc2, 1, v1)
            FMA4(a3, wc3, 0, v0) FMA4(a3, wc3, 1, v1)
            BFLY8(a0) BFLY8(a1) BFLY8(a2) BFLY8(a3)
            a0 += bC0; a1 += bC1; a2 += bC2; a3 += bC3;
            float tg = fsig(a2 + a3);
            float f1 = ftanh(a0), f2 = ftanh(a1);
            float o = f1 + tg * (f2 - f1);
            if (k == 0) { z1[row] = o; zL[13 + row] = o; }
        } else {
            if (lts == 62 && (ts + 2) < TSTEPS) {
                // refill x tile [ts+2, ts+66) into buffer par^1
                int i = t - 280;                       // 0..231; use 0..207
                if (i < 208) {
                    float4 v = *(const float4*)(x + xbase + (long)(ts + 2) * 13 + 4 * i);
                    float* dst = par ? xt0 : xt1;
                    *(float4*)&dst[4 * i] = v;
                }
            }
            if (lts == 0 && ts > 0) {
                // flush out tile for steps [ts-64, ts) from buffer par^1
                int i = t - 280;                       // 0..95 used
                if (i < 96) {
                    const float* src = par ? ot0 : ot1;
                    float4 v = *(const float4*)&src[4 * i];
                    *(float4*)(out + obase + (long)(ts - XT) * 6 + 4 * i) = v;
                }
            }
        }
        __syncthreads();

        // ---- phase 3: CfC1 (lanes 280..463) ----
        if (grp == 1) {
            const float4* zc = (const float4*)(z1 + 8 * k);
            float4 v0 = zc[0], v1 = zc[1];
            float a0 = 0.f, a1 = 0.f, a2 = 0.f, a3 = 0.f;
            FMA4(a0, wc0, 0, v0) FMA4(a0, wc0, 1, v1)
            FMA4(a1, wc1, 0, v0) FMA4(a1, wc1, 1, v1)
            FMA4(a2, wc2, 0, v0) FMA4(a2, wc2, 1, v1)
            FMA4(a3, wc3, 0, v0) FMA4(a3, wc3, 1, v1)
            BFLY8(a0) BFLY8(a1) BFLY8(a2) BFLY8(a3)
            a0 += bC0; a1 += bC1; a2 += bC2; a3 += bC3;
            float tg = fsig(a2 + a3);
            float f1 = ftanh(a0), f2 = ftanh(a1);
            float o = f1 + tg * (f2 - f1);
            if (k == 0) { z2[row] = o; zL[48 + row] = o; }
        }
        __syncthreads();

        // ---- phase 4: CfC2 (lanes 464..511) + x_{t+1} copy from tile ----
        if (grp == 2) {
            const float4* zc = (const float4*)(z2 + 4 * k);
            float4 v0 = zc[0];
            float a0 = 0.f, a1 = 0.f, a2 = 0.f, a3 = 0.f;
            FMA4(a0, wc0, 0, v0)
            FMA4(a1, wc1, 0, v0)
            FMA4(a2, wc2, 0, v0)
            FMA4(a3, wc3, 0, v0)
            BFLY8(a0) BFLY8(a1) BFLY8(a2) BFLY8(a3)
            a0 += bC0; a1 += bC1; a2 += bC2; a3 += bC3;
            float tg = fsig(a2 + a3);
            float f1 = ftanh(a0), f2 = ftanh(a1);
            float o = f1 + tg * (f2 - f1);
            if (k == 0) {
                zL[71 + row] = o;                      // new h[58:64]
                float* ob = par ? ot1 : ot0;           // out tile (LDS only)
                ob[lts * 6 + row] = o;
            }
        } else if (t < 13 && (ts + 1) < TSTEPS) {
            const float* xb = (((ts + 1) >> 6) & 1) ? xt1 : xt0;
            zL[t] = xb[((ts + 1) & 63) * 13 + t];      // commit x_{t+1}
        }
        __syncthreads();
    }

    // ---- epilogue: flush the last out tile (steps 4032..4095, buffer 1) ----
    {
        int i = t - 280;
        if (i >= 0 && i < 96) {
            float4 v = *(const float4*)&ot1[4 * i];
            *(float4*)(out + obase + (long)(TSTEPS - XT) * 6 + 4 * i) = v;
        }
    }
}

// ---- head: rewrite pred in place, write unc ----
#define S_GW1 0
#define S_GB1 192
#define S_GW2 224
#define S_GB2 320
#define S_AW1 323
#define S_AB1 515
#define S_AW2 547
#define S_AB2 643
#define S_UW1 646
#define S_UB1 742
#define S_UW2 758
#define S_UB2 854
#define S_TOT 860

__global__ __launch_bounds__(256)
void head_kernel(const float* __restrict__ gw1, const float* __restrict__ gb1,
                 const float* __restrict__ gw2, const float* __restrict__ gb2,
                 const float* __restrict__ aw1, const float* __restrict__ ab1,
                 const float* __restrict__ aw2, const float* __restrict__ ab2,
                 const float* __restrict__ uw1, const float* __restrict__ ub1,
                 const float* __restrict__ uw2, const float* __restrict__ ub2,
                 float* __restrict__ out)
{
    __shared__ float s[S_TOT];
    const int t = threadIdx.x;
    if (t < 192) { s[S_GW1 + t] = gw1[t]; s[S_AW1 + t] = aw1[t]; }
    if (t < 96)  { s[S_GW2 + t] = gw2[t]; s[S_AW2 + t] = aw2[t];
                   s[S_UW1 + t] = uw1[t]; s[S_UW2 + t] = uw2[t]; }
    if (t < 32)  { s[S_GB1 + t] = gb1[t]; s[S_AB1 + t] = ab1[t]; }
    if (t < 16)  { s[S_UB1 + t] = ub1[t]; }
    if (t < 3)   { s[S_GB2 + t] = gb2[t]; s[S_AB2 + t] = ab2[t]; }
    if (t < 6)   { s[S_UB2 + t] = ub2[t]; }
    __syncthreads();

    const long p = (long)blockIdx.x * 256 + t;   // < B*T exactly
    const long base = p * 6;
    float m0 = out[base+0], m1 = out[base+1], m2 = out[base+2];
    float m3 = out[base+3], m4 = out[base+4], m5 = out[base+5];

    float gy0 = s[S_GB2+0], gy1 = s[S_GB2+1], gy2 = s[S_GB2+2];
    float ac0 = s[S_AB2+0], ac1 = s[S_AB2+1], ac2 = s[S_AB2+2];
    #pragma unroll
    for (int i = 0; i < 32; ++i) {
        float hg = s[S_GB1+i] + s[S_GW1+i*6+0]*m0 + s[S_GW1+i*6+1]*m1
                 + s[S_GW1+i*6+2]*m2 + s[S_GW1+i*6+3]*m3
                 + s[S_GW1+i*6+4]*m4 + s[S_GW1+i*6+5]*m5;
        hg = ftanh(hg);
        gy0 += s[S_GW2+i]*hg; gy1 += s[S_GW2+32+i]*hg; gy2 += s[S_GW2+64+i]*hg;
        float ha = s[S_AB1+i] + s[S_AW1+i*6+0]*m0 + s[S_AW1+i*6+1]*m1
                 + s[S_AW1+i*6+2]*m2 + s[S_AW1+i*6+3]*m3
                 + s[S_AW1+i*6+4]*m4 + s[S_AW1+i*6+5]*m5;
        ha = ftanh(ha);
        ac0 += s[S_AW2+i]*ha; ac1 += s[S_AW2+32+i]*ha; ac2 += s[S_AW2+64+i]*ha;
    }
    float u0 = s[S_UB2+0], u1 = s[S_UB2+1], u2 = s[S_UB2+2];
    float u3 = s[S_UB2+3], u4 = s[S_UB2+4], u5 = s[S_UB2+5];
    #pragma unroll
    for (int i = 0; i < 16; ++i) {
        float hu = s[S_UB1+i] + s[S_UW1+i*6+0]*m0 + s[S_UW1+i*6+1]*m1
                 + s[S_UW1+i*6+2]*m2 + s[S_UW1+i*6+3]*m3
                 + s[S_UW1+i*6+4]*m4 + s[S_UW1+i*6+5]*m5;
        hu = fmaxf(hu, 0.f);
        u0 += s[S_UW2+i]*hu;      u1 += s[S_UW2+16+i]*hu; u2 += s[S_UW2+32+i]*hu;
        u3 += s[S_UW2+48+i]*hu;   u4 += s[S_UW2+64+i]*hu; u5 += s[S_UW2+80+i]*hu;
    }
    out[base+0] = gy0; out[base+1] = gy1; out[base+2] = gy2;
    out[base+3] = ac0; out[base+4] = ac1; out[base+5] = ac2;
    const long uoff = (long)BATCH * TSTEPS * 6;
    out[uoff+base+0] = fsoftplus(u0); out[uoff+base+1] = fsoftplus(u1);
    out[uoff+base+2] = fsoftplus(u2); out[uoff+base+3] = fsoftplus(u3);
    out[uoff+base+4] = fsoftplus(u4); out[uoff+base+5] = fsoftplus(u5);
}

extern "C" void kernel_launch(void* const* d_in, const int* in_sizes, int n_in,
                              void* d_out, int out_size, void* d_ws, size_t ws_size,
                              hipStream_t stream) {
    const float* x       = (const float*)d_in[0];
    const float* lstm_wi = (const float*)d_in[1];
    const float* lstm_wh = (const float*)d_in[2];
    const float* lstm_b  = (const float*)d_in[3];
    const float* c0w1 = (const float*)d_in[4];
    const float* c0w2 = (const float*)d_in[5];
    const float* c0wa = (const float*)d_in[6];
    const float* c0wb = (const float*)d_in[7];
    const float* c0b1 = (const float*)d_in[8];
    const float* c0b2 = (const float*)d_in[9];
    const float* c0ba = (const float*)d_in[10];
    const float* c0bb = (const float*)d_in[11];
    const float* c1w1 = (const float*)d_in[12];
    const float* c1w2 = (const float*)d_in[13];
    const float* c1wa = (const float*)d_in[14];
    const float* c1wb = (const float*)d_in[15];
    const float* c1b1 = (const float*)d_in[16];
    const float* c1b2 = (const float*)d_in[17];
    const float* c1ba = (const float*)d_in[18];
    const float* c1bb = (const float*)d_in[19];
    const float* c2w1 = (const float*)d_in[20];
    const float* c2w2 = (const float*)d_in[21];
    const float* c2wa = (const float*)d_in[22];
    const float* c2wb = (const float*)d_in[23];
    const float* c2b1 = (const float*)d_in[24];
    const float* c2b2 = (const float*)d_in[25];
    const float* c2ba = (const float*)d_in[26];
    const float* c2bb = (const float*)d_in[27];
    const float* gw1 = (const float*)d_in[28];
    const float* gb1 = (const float*)d_in[29];
    const float* gw2 = (const float*)d_in[30];
    const float* gb2 = (const float*)d_in[31];
    const float* aw1 = (const float*)d_in[32];
    const float* ab1 = (const float*)d_in[33];
    const float* aw2 = (const float*)d_in[34];
    const float* ab2 = (const float*)d_in[35];
    const float* uw1 = (const float*)d_in[36];
    const float* ub1 = (const float*)d_in[37];
    const float* uw2 = (const float*)d_in[38];
    const float* ub2 = (const float*)d_in[39];
    float* out = (float*)d_out;

    rnn_kernel<<<BATCH, 512, 0, stream>>>(x, lstm_wi, lstm_wh, lstm_b,
        c0w1, c0w2, c0wa, c0wb, c0b1, c0b2, c0ba, c0bb,
        c1w1, c1w2, c1wa, c1wb, c1b1, c1b2, c1ba, c1bb,
        c2w1, c2w2, c2wa, c2wb, c2b1, c2b2, c2ba, c2bb, out);

    head_kernel<<<(BATCH * TSTEPS) / 256, 256, 0, stream>>>(
        gw1, gb1, gw2, gb2, aw1, ab1, aw2, ab2, uw1, ub1, uw2, ub2, out);
}

// Round 10
// 5322.982 us; speedup vs baseline: 1.2816x; 1.0244x over previous
//
#include <hip/hip_runtime.h>
#include <math.h>

#define BATCH 128
#define TSTEPS 4096
#define INDIM 13
#define XT 64   // steps per x/out LDS tile

// LDS layout (floats):
//  state[0:256):  zL[0:96) | z0 @96 | z1 @160 | z2 @224   (zero-initialized)
//  xt0 @256 (832) | xt1 @1088 (832)   x tiles, double-buffered (64 steps x 13)
//  ot0 @1920 (384) | ot1 @2304 (384)  out tiles, double-buffered (64 steps x 6)
// 256 threads (4 waves, 1 wave/SIMD via __launch_bounds__(256,1)): quad
// K-split, 2-DPP butterfly, no global memory in the steady-state loop.

__device__ __forceinline__ float fsig(float x) {
    return __builtin_amdgcn_rcpf(1.f + __expf(-x));
}
__device__ __forceinline__ float ftanh(float x) {
    float s = fsig(x + x);
    return s + s - 1.f;
}
__device__ __forceinline__ float fsoftplus(float x) {
    return (x > 15.f) ? x : __logf(1.f + __expf(x));
}

// quad exchanges via DPP (VALU latency, no LDS pipe)
__device__ __forceinline__ float qxor1(float v) {   // quad_perm [1,0,3,2]
    return __int_as_float(__builtin_amdgcn_update_dpp(
        0, __float_as_int(v), 0xB1, 0xF, 0xF, true));
}
__device__ __forceinline__ float qxor2(float v) {   // quad_perm [2,3,0,1]
    return __int_as_float(__builtin_amdgcn_update_dpp(
        0, __float_as_int(v), 0x4E, 0xF, 0xF, true));
}
// 4-lane butterfly allreduce, 2 DPP stages, bit-identical on all 4 lanes.
#define BFLY4(a) { a += qxor1(a); a += qxor2(a); }

// acc += dot(float4 zv, 4 named weight scalars W_q_{0..3})
#define FMA4(acc, W, q, zv) { acc += zv.x * W##_##q##_0; acc += zv.y * W##_##q##_1; \
                              acc += zv.z * W##_##q##_2; acc += zv.w * W##_##q##_3; }

__global__ __launch_bounds__(256, 1)
void rnn_kernel(const float* __restrict__ x,
                const float* __restrict__ lstm_wi, const float* __restrict__ lstm_wh,
                const float* __restrict__ lstm_b,
                const float* __restrict__ c0w1, const float* __restrict__ c0w2,
                const float* __restrict__ c0wa, const float* __restrict__ c0wb,
                const float* __restrict__ c0b1, const float* __restrict__ c0b2,
                const float* __restrict__ c0ba, const float* __restrict__ c0bb,
                const float* __restrict__ c1w1, const float* __restrict__ c1w2,
                const float* __restrict__ c1wa, const float* __restrict__ c1wb,
                const float* __restrict__ c1b1, const float* __restrict__ c1b2,
                const float* __restrict__ c1ba, const float* __restrict__ c1bb,
                const float* __restrict__ c2w1, const float* __restrict__ c2w2,
                const float* __restrict__ c2wa, const float* __restrict__ c2wb,
                const float* __restrict__ c2b1, const float* __restrict__ c2b2,
                const float* __restrict__ c2ba, const float* __restrict__ c2bb,
                float* __restrict__ out)
{
    const int bb = blockIdx.x;
    const int t  = threadIdx.x;     // 0..255
    const int k  = t & 3;           // K-chunk slot within the quad
    const int u  = t >> 2;          // unit / row-group index 0..63

    __shared__ __align__(16) float smem[2688];
    float* zL  = smem;
    float* z0  = smem + 96;
    float* z1  = smem + 160;
    float* z2  = smem + 224;
    float* xt0 = smem + 256;
    float* xt1 = smem + 1088;
    float* ot0 = smem + 1920;
    float* ot1 = smem + 2304;

    const long xbase = (long)bb * TSTEPS * INDIM;
    const long obase = (long)bb * TSTEPS * 6;

    // ---- LSTM weights: lane (u,k) holds cols [24k,24k+24) of all 4 gate rows
    auto lwf = [&](int A, int c) -> float {
        int r = A * 64 + u;
        return (c < 13) ? lstm_wi[r * 13 + c]
             : (c < 77) ? lstm_wh[r * 64 + (c - 13)] : 0.f;
    };
#define DEF_WL(A,q) \
    float wl##A##_##q##_0 = lwf(A, 24*k + 4*q + 0); \
    float wl##A##_##q##_1 = lwf(A, 24*k + 4*q + 1); \
    float wl##A##_##q##_2 = lwf(A, 24*k + 4*q + 2); \
    float wl##A##_##q##_3 = lwf(A, 24*k + 4*q + 3);
    DEF_WL(0,0) DEF_WL(0,1) DEF_WL(0,2) DEF_WL(0,3) DEF_WL(0,4) DEF_WL(0,5)
    DEF_WL(1,0) DEF_WL(1,1) DEF_WL(1,2) DEF_WL(1,3) DEF_WL(1,4) DEF_WL(1,5)
    DEF_WL(2,0) DEF_WL(2,1) DEF_WL(2,2) DEF_WL(2,3) DEF_WL(2,4) DEF_WL(2,5)
    DEF_WL(3,0) DEF_WL(3,1) DEF_WL(3,2) DEF_WL(3,3) DEF_WL(3,4) DEF_WL(3,5)
#undef DEF_WL
    const float bL0 = lstm_b[u];
    const float bL1 = lstm_b[64 + u];
    const float bL2 = lstm_b[128 + u];
    const float bL3 = lstm_b[192 + u];

    // ---- CfC weights: quad groups (disjoint lane sets, one name overlay)
    // grp0 (u<35):  row u,    len 48, chunk 12 at 12k (3 float4)
    // grp1 (u<58):  row u-35, len 58, chunk 16 at 16k (4 float4)
    // grp2 (u>=58): row u-58, len 29, chunk 8  at 8k  (2 float4)
    const int grp  = (u < 35) ? 0 : (u < 58) ? 1 : 2;
    const int row  = (grp == 0) ? u : (grp == 1) ? (u - 35) : (u - 58);
    const int rl   = (grp == 0) ? 48 : (grp == 1) ? 58 : 29;
    const int clen = (grp == 0) ? 12 : (grp == 1) ? 16 : 8;
    const int cb   = clen * k;
    const float *W0p, *W1p, *W2p, *W3p;
    float bC0, bC1, bC2, bC3;
    if (grp == 0) {
        W0p = c0w1 + row * 48; W1p = c0w2 + row * 48;
        W2p = c0wa + row * 48; W3p = c0wb + row * 48;
        bC0 = c0b1[row]; bC1 = c0b2[row]; bC2 = c0ba[row]; bC3 = c0bb[row];
    } else if (grp == 1) {
        W0p = c1w1 + row * 58; W1p = c1w2 + row * 58;
        W2p = c1wa + row * 58; W3p = c1wb + row * 58;
        bC0 = c1b1[row]; bC1 = c1b2[row]; bC2 = c1ba[row]; bC3 = c1bb[row];
    } else {
        W0p = c2w1 + row * 29; W1p = c2w2 + row * 29;
        W2p = c2wa + row * 29; W3p = c2wb + row * 29;
        bC0 = c2b1[row]; bC1 = c2b2[row]; bC2 = c2ba[row]; bC3 = c2bb[row];
    }
    auto cwf = [&](const float* W, int c) -> float {
        int cc = cb + c;
        return (c < clen && cc < rl) ? W[cc] : 0.f;
    };
#define DEF_WC(A,q) \
    float wc##A##_##q##_0 = cwf(W##A##p, 4*q + 0); \
    float wc##A##_##q##_1 = cwf(W##A##p, 4*q + 1); \
    float wc##A##_##q##_2 = cwf(W##A##p, 4*q + 2); \
    float wc##A##_##q##_3 = cwf(W##A##p, 4*q + 3);
    DEF_WC(0,0) DEF_WC(0,1) DEF_WC(0,2) DEF_WC(0,3)
    DEF_WC(1,0) DEF_WC(1,1) DEF_WC(1,2) DEF_WC(1,3)
    DEF_WC(2,0) DEF_WC(2,1) DEF_WC(2,2) DEF_WC(2,3)
    DEF_WC(3,0) DEF_WC(3,1) DEF_WC(3,2) DEF_WC(3,3)
#undef DEF_WC

    float creg = 0.f;                         // cell state, replicated per quad

    // ---- prologue: zero state, load x tile 0, seed x_0 ----
    smem[t] = 0.f;
    if (t < 208) {                            // 208 float4 = 64 steps x 13
        float4 xi = *(const float4*)(x + xbase + 4 * t);
        *(float4*)&xt0[4 * t] = xi;
    }
    if (t < 13) { float x0 = x[xbase + t]; zL[t] = x0; z0[t] = x0; }
    __syncthreads();

    #pragma unroll 1
    for (int ts = 0; ts < TSTEPS; ++ts) {
        const int par = (ts >> 6) & 1;
        const int lts = ts & 63;

        // ---- phase 1: LSTM (all 256 lanes; K-split-4 by k) ----
        {
            const float4* zc = (const float4*)(zL + 24 * k);
            float4 q0 = zc[0], q1 = zc[1], q2 = zc[2],
                   q3 = zc[3], q4 = zc[4], q5 = zc[5];
            float a0 = 0.f, a1 = 0.f, a2 = 0.f, a3 = 0.f;
            FMA4(a0, wl0, 0, q0) FMA4(a0, wl0, 1, q1) FMA4(a0, wl0, 2, q2)
            FMA4(a0, wl0, 3, q3) FMA4(a0, wl0, 4, q4) FMA4(a0, wl0, 5, q5)
            FMA4(a1, wl1, 0, q0) FMA4(a1, wl1, 1, q1) FMA4(a1, wl1, 2, q2)
            FMA4(a1, wl1, 3, q3) FMA4(a1, wl1, 4, q4) FMA4(a1, wl1, 5, q5)
            FMA4(a2, wl2, 0, q0) FMA4(a2, wl2, 1, q1) FMA4(a2, wl2, 2, q2)
            FMA4(a2, wl2, 3, q3) FMA4(a2, wl2, 4, q4) FMA4(a2, wl2, 5, q5)
            FMA4(a3, wl3, 0, q0) FMA4(a3, wl3, 1, q1) FMA4(a3, wl3, 2, q2)
            FMA4(a3, wl3, 3, q3) FMA4(a3, wl3, 4, q4) FMA4(a3, wl3, 5, q5)
            BFLY4(a0) BFLY4(a1) BFLY4(a2) BFLY4(a3)
            a0 += bL0; a1 += bL1; a2 += bL2; a3 += bL3;   // ia, ig, fg, og
            float cn = creg * fsig(a2 + 1.f) + ftanh(a0) * fsig(a1);
            creg = cn;                      // bit-identical on all 4 quad lanes
            float hl = ftanh(cn) * fsig(a3);
            if (k == 0) {
                if (u < 35)      z0[13 + u] = hl;   // h0
                else if (u < 58) z1[u]      = hl;   // h1 at z1[35..57]
                else             z2[u - 35] = hl;   // h2 at z2[23..28]
            }
        }
        __syncthreads();

        // ---- phase 2: CfC0 (lanes 0..139) || tile refill / out flush ----
        if (grp == 0) {
            const float4* zc = (const float4*)(z0 + 12 * k);
            float4 v0 = zc[0], v1 = zc[1], v2 = zc[2];
            float a0 = 0.f, a1 = 0.f, a2 = 0.f, a3 = 0.f;
            FMA4(a0, wc0, 0, v0) FMA4(a0, wc0, 1, v1) FMA4(a0, wc0, 2, v2)
            FMA4(a1, wc1, 0, v0) FMA4(a1, wc1, 1, v1) FMA4(a1, wc1, 2, v2)
            FMA4(a2, wc2, 0, v0) FMA4(a2, wc2, 1, v1) FMA4(a2, wc2, 2, v2)
            FMA4(a3, wc3, 0, v0) FMA4(a3, wc3, 1, v1) FMA4(a3, wc3, 2, v2)
            BFLY4(a0) BFLY4(a1) BFLY4(a2) BFLY4(a3)
            a0 += bC0; a1 += bC1; a2 += bC2; a3 += bC3;
            float tg = fsig(a2 + a3);
            float f1 = ftanh(a0), f2 = ftanh(a1);
            float o = f1 + tg * (f2 - f1);
            if (k == 0) { z1[row] = o; zL[13 + row] = o; }
        } else {
            if (lts == 62 && (ts + 2) < TSTEPS) {
                // refill x tile [ts+2, ts+66) into buffer par^1 (2 f4/lane)
                int i = (t - 140) * 2;                 // lanes 140..243
                float* dst = par ? xt0 : xt1;
                const float* src = x + xbase + (long)(ts + 2) * 13;
                if (i < 208)     *(float4*)&dst[4*i]     = *(const float4*)(src + 4*i);
                if (i + 1 < 208) *(float4*)&dst[4*(i+1)] = *(const float4*)(src + 4*(i+1));
            }
            if (lts == 0 && ts > 0) {
                // flush out tile for steps [ts-64, ts) from buffer par^1
                int i = t - 140;                       // 0..95 used
                if (i < 96) {
                    const float* src = par ? ot0 : ot1;
                    float4 v = *(const float4*)&src[4 * i];
                    *(float4*)(out + obase + (long)(ts - XT) * 6 + 4 * i) = v;
                }
            }
        }
        __syncthreads();

        // ---- phase 3: CfC1 (lanes 140..231) ----
        if (grp == 1) {
            const float4* zc = (const float4*)(z1 + 16 * k);
            float4 v0 = zc[0], v1 = zc[1], v2 = zc[2], v3 = zc[3];
            float a0 = 0.f, a1 = 0.f, a2 = 0.f, a3 = 0.f;
            FMA4(a0, wc0, 0, v0) FMA4(a0, wc0, 1, v1) FMA4(a0, wc0, 2, v2) FMA4(a0, wc0, 3, v3)
            FMA4(a1, wc1, 0, v0) FMA4(a1, wc1, 1, v1) FMA4(a1, wc1, 2, v2) FMA4(a1, wc1, 3, v3)
            FMA4(a2, wc2, 0, v0) FMA4(a2, wc2, 1, v1) FMA4(a2, wc2, 2, v2) FMA4(a2, wc2, 3, v3)
            FMA4(a3, wc3, 0, v0) FMA4(a3, wc3, 1, v1) FMA4(a3, wc3, 2, v2) FMA4(a3, wc3, 3, v3)
            BFLY4(a0) BFLY4(a1) BFLY4(a2) BFLY4(a3)
            a0 += bC0; a1 += bC1; a2 += bC2; a3 += bC3;
            float tg = fsig(a2 + a3);
            float f1 = ftanh(a0), f2 = ftanh(a1);
            float o = f1 + tg * (f2 - f1);
            if (k == 0) { z2[row] = o; zL[48 + row] = o; }
        }
        __syncthreads();

        // ---- phase 4: CfC2 (lanes 232..255) + x_{t+1} commit from tile ----
        if (grp == 2) {
            const float4* zc = (const float4*)(z2 + 8 * k);
            float4 v0 = zc[0], v1 = zc[1];
            float a0 = 0.f, a1 = 0.f, a2 = 0.f, a3 = 0.f;
            FMA4(a0, wc0, 0, v0) FMA4(a0, wc0, 1, v1)
            FMA4(a1, wc1, 0, v0) FMA4(a1, wc1, 1, v1)
            FMA4(a2, wc2, 0, v0) FMA4(a2, wc2, 1, v1)
            FMA4(a3, wc3, 0, v0) FMA4(a3, wc3, 1, v1)
            BFLY4(a0) BFLY4(a1) BFLY4(a2) BFLY4(a3)
            a0 += bC0; a1 += bC1; a2 += bC2; a3 += bC3;
            float tg = fsig(a2 + a3);
            float f1 = ftanh(a0), f2 = ftanh(a1);
            float o = f1 + tg * (f2 - f1);
            if (k == 0) {
                zL[71 + row] = o;                      // new h[58:64]
                float* ob = par ? ot1 : ot0;           // out tile (LDS only)
                ob[lts * 6 + row] = o;
            }
        } else if (t < 13 && (ts + 1) < TSTEPS) {
            const float* xb = (((ts + 1) >> 6) & 1) ? xt1 : xt0;
            float xn = xb[((ts + 1) & 63) * 13 + t];
            zL[t] = xn; z0[t] = xn;                    // commit x_{t+1}
        }
        __syncthreads();
    }

    // ---- epilogue: flush the last out tile (steps 4032..4095, buffer 1) ----
    if (t < 96) {
        float4 v = *(const float4*)&ot1[4 * t];
        *(float4*)(out + obase + (long)(TSTEPS - XT) * 6 + 4 * t) = v;
    }
}

// ---- head: rewrite pred in place, write unc ----
#define S_GW1 0
#define S_GB1 192
#define S_GW2 224
#define S_GB2 320
#define S_AW1 323
#define S_AB1 515
#define S_AW2 547
#define S_AB2 643
#define S_UW1 646
#define S_UB1 742
#define S_UW2 758
#define S_UB2 854
#define S_TOT 860

__global__ __launch_bounds__(256)
void head_kernel(const float* __restrict__ gw1, const float* __restrict__ gb1,
                 const float* __restrict__ gw2, const float* __restrict__ gb2,
                 const float* __restrict__ aw1, const float* __restrict__ ab1,
                 const float* __restrict__ aw2, const float* __restrict__ ab2,
                 const float* __restrict__ uw1, const float* __restrict__ ub1,
                 const float* __restrict__ uw2, const float* __restrict__ ub2,
                 float* __restrict__ out)
{
    __shared__ float s[S_TOT];
    const int t = threadIdx.x;
    if (t < 192) { s[S_GW1 + t] = gw1[t]; s[S_AW1 + t] = aw1[t]; }
    if (t < 96)  { s[S_GW2 + t] = gw2[t]; s[S_AW2 + t] = aw2[t];
                   s[S_UW1 + t] = uw1[t]; s[S_UW2 + t] = uw2[t]; }
    if (t < 32)  { s[S_GB1 + t] = gb1[t]; s[S_AB1 + t] = ab1[t]; }
    if (t < 16)  { s[S_UB1 + t] = ub1[t]; }
    if (t < 3)   { s[S_GB2 + t] = gb2[t]; s[S_AB2 + t] = ab2[t]; }
    if (t < 6)   { s[S_UB2 + t] = ub2[t]; }
    __syncthreads();

    const long p = (long)blockIdx.x * 256 + t;   // < B*T exactly
    const long base = p * 6;
    float m0 = out[base+0], m1 = out[base+1], m2 = out[base+2];
    float m3 = out[base+3], m4 = out[base+4], m5 = out[base+5];

    float gy0 = s[S_GB2+0], gy1 = s[S_GB2+1], gy2 = s[S_GB2+2];
    float ac0 = s[S_AB2+0], ac1 = s[S_AB2+1], ac2 = s[S_AB2+2];
    #pragma unroll
    for (int i = 0; i < 32; ++i) {
        float hg = s[S_GB1+i] + s[S_GW1+i*6+0]*m0 + s[S_GW1+i*6+1]*m1
                 + s[S_GW1+i*6+2]*m2 + s[S_GW1+i*6+3]*m3
                 + s[S_GW1+i*6+4]*m4 + s[S_GW1+i*6+5]*m5;
        hg = ftanh(hg);
        gy0 += s[S_GW2+i]*hg; gy1 += s[S_GW2+32+i]*hg; gy2 += s[S_GW2+64+i]*hg;
        float ha = s[S_AB1+i] + s[S_AW1+i*6+0]*m0 + s[S_AW1+i*6+1]*m1
                 + s[S_AW1+i*6+2]*m2 + s[S_AW1+i*6+3]*m3
                 + s[S_AW1+i*6+4]*m4 + s[S_AW1+i*6+5]*m5;
        ha = ftanh(ha);
        ac0 += s[S_AW2+i]*ha; ac1 += s[S_AW2+32+i]*ha; ac2 += s[S_AW2+64+i]*ha;
    }
    float u0 = s[S_UB2+0], u1 = s[S_UB2+1], u2 = s[S_UB2+2];
    float u3 = s[S_UB2+3], u4 = s[S_UB2+4], u5 = s[S_UB2+5];
    #pragma unroll
    for (int i = 0; i < 16; ++i) {
        float hu = s[S_UB1+i] + s[S_UW1+i*6+0]*m0 + s[S_UW1+i*6+1]*m1
                 + s[S_UW1+i*6+2]*m2 + s[S_UW1+i*6+3]*m3
                 + s[S_UW1+i*6+4]*m4 + s[S_UW1+i*6+5]*m5;
        hu = fmaxf(hu, 0.f);
        u0 += s[S_UW2+i]*hu;      u1 += s[S_UW2+16+i]*hu; u2 += s[S_UW2+32+i]*hu;
        u3 += s[S_UW2+48+i]*hu;   u4 += s[S_UW2+64+i]*hu; u5 += s[S_UW2+80+i]*hu;
    }
    out[base+0] = gy0; out[base+1] = gy1; out[base+2] = gy2;
    out[base+3] = ac0; out[base+4] = ac1; out[base+5] = ac2;
    const long uoff = (long)BATCH * TSTEPS * 6;
    out[uoff+base+0] = fsoftplus(u0); out[uoff+base+1] = fsoftplus(u1);
    out[uoff+base+2] = fsoftplus(u2); out[uoff+base+3] = fsoftplus(u3);
    out[uoff+base+4] = fsoftplus(u4); out[uoff+base+5] = fsoftplus(u5);
}

extern "C" void kernel_launch(void* const* d_in, const int* in_sizes, int n_in,
                              void* d_out, int out_size, void* d_ws, size_t ws_size,
                              hipStream_t stream) {
    const float* x       = (const float*)d_in[0];
    const float* lstm_wi = (const float*)d_in[1];
    const float* lstm_wh = (const float*)d_in[2];
    const float* lstm_b  = (const float*)d_in[3];
    const float* c0w1 = (const float*)d_in[4];
    const float* c0w2 = (const float*)d_in[5];
    const float* c0wa = (const float*)d_in[6];
    const float* c0wb = (const float*)d_in[7];
    const float* c0b1 = (const float*)d_in[8];
    const float* c0b2 = (const float*)d_in[9];
    const float* c0ba = (const float*)d_in[10];
    const float* c0bb = (const float*)d_in[11];
    const float* c1w1 = (const float*)d_in[12];
    const float* c1w2 = (const float*)d_in[13];
    const float* c1wa = (const float*)d_in[14];
    const float* c1wb = (const float*)d_in[15];
    const float* c1b1 = (const float*)d_in[16];
    const float* c1b2 = (const float*)d_in[17];
    const float* c1ba = (const float*)d_in[18];
    const float* c1bb = (const float*)d_in[19];
    const float* c2w1 = (const float*)d_in[20];
    const float* c2w2 = (const float*)d_in[21];
    const float* c2wa = (const float*)d_in[22];
    const float* c2wb = (const float*)d_in[23];
    const float* c2b1 = (const float*)d_in[24];
    const float* c2b2 = (const float*)d_in[25];
    const float* c2ba = (const float*)d_in[26];
    const float* c2bb = (const float*)d_in[27];
    const float* gw1 = (const float*)d_in[28];
    const float* gb1 = (const float*)d_in[29];
    const float* gw2 = (const float*)d_in[30];
    const float* gb2 = (const float*)d_in[31];
    const float* aw1 = (const float*)d_in[32];
    const float* ab1 = (const float*)d_in[33];
    const float* aw2 = (const float*)d_in[34];
    const float* ab2 = (const float*)d_in[35];
    const float* uw1 = (const float*)d_in[36];
    const float* ub1 = (const float*)d_in[37];
    const float* uw2 = (const float*)d_in[38];
    const float* ub2 = (const float*)d_in[39];
    float* out = (float*)d_out;

    rnn_kernel<<<BATCH, 256, 0, stream>>>(x, lstm_wi, lstm_wh, lstm_b,
        c0w1, c0w2, c0wa, c0wb, c0b1, c0b2, c0ba, c0bb,
        c1w1, c1w2, c1wa, c1wb, c1b1, c1b2, c1ba, c1bb,
        c2w1, c2w2, c2wa, c2wb, c2b1, c2b2, c2ba, c2bb, out);

    head_kernel<<<(BATCH * TSTEPS) / 256, 256, 0, stream>>>(
        gw1, gb1, gw2, gb2, aw1, ab1, aw2, ab2, uw1, ub1, uw2, ub2, out);
}